// Round 12
// baseline (321.473 us; speedup 1.0000x reference)
//
#include <hip/hip_runtime.h>
#include <hip/hip_bf16.h>

// Problem constants
#define GAT_IN   128
#define GAT_OUT  128   // H*C
#define GAT_H    4
#define GAT_C    32
#define NEG_SLOPE 0.2f
#define BUCKET   48    // per-node edge slot capacity; P(Poisson(12) >= 48) ~ 3e-15
#define NB       196   // coarse buckets = ceil(50000/256), bucket = col>>8
#define CAP      4096  // entries per coarse bucket (mean 3061, sigma 55 -> 18 sigma)
#define E_B      2048  // edges per pass1 block (293 blocks)
#define EPTH     8     // E_B / 256

typedef __attribute__((ext_vector_type(8))) short bf16x8;
typedef __attribute__((ext_vector_type(4))) float f32x4;
union U4 { uint4 u; bf16x8 v; };

static __device__ __forceinline__ unsigned int pack_bf16(float lo, float hi) {
    __hip_bfloat16 a = __float2bfloat16(lo);   // RTN
    __hip_bfloat16 b = __float2bfloat16(hi);
    unsigned short ua = *reinterpret_cast<unsigned short*>(&a);
    unsigned short ub = *reinterpret_cast<unsigned short*>(&b);
    return (unsigned int)ua | ((unsigned int)ub << 16);
}

// ---------------------------------------------------------------------------
// Kernel 1: Bezier param interp (32 blocks) + zero the NB coarse-bucket
// claim counters (block 0). (UNCHANGED from R10.)
// ---------------------------------------------------------------------------
__global__ __launch_bounds__(256) void interp_kernel(
    const float* __restrict__ coeffs,
    const float* __restrict__ lw,   // [3,128,128]
    const float* __restrict__ lb,   // [3,128]
    const float* __restrict__ asr,  // [3,1,4,32]
    const float* __restrict__ ads,  // [3,1,4,32]
    unsigned int* __restrict__ wfrag,  // 8192 uints (32 KB)
    float* __restrict__ biasc,
    float* __restrict__ asrc, float* __restrict__ adst,
    int* __restrict__ bucket_pos)      // [NB] claim counters -> zero
{
    int b = blockIdx.x, t = threadIdx.x;
    int i = b * 256 + t;                    // 0..8191
    float c0 = coeffs[0], c1 = coeffs[1], c2 = coeffs[2];
    int lane = (i >> 2) & 63;
    int nk   = i >> 8;           // nt*4 + ks
    int jw   = i & 3;
    int nt = nk >> 2, ks = nk & 3;
    int o = nt * 16 + (lane & 15);
    int k = ks * 32 + (lane >> 4) * 8 + jw * 2;
    int idx = o * 128 + k;
    float w0 = c0 * lw[idx]     + c1 * lw[16384 + idx]     + c2 * lw[32768 + idx];
    float w1 = c0 * lw[idx + 1] + c1 * lw[16384 + idx + 1] + c2 * lw[32768 + idx + 1];
    wfrag[i] = pack_bf16(w0, w1);
    if (b == 0) {
        if (t < 128) {
            biasc[t] = c0 * lb[t]  + c1 * lb[128 + t]  + c2 * lb[256 + t];
            asrc[t]  = c0 * asr[t] + c1 * asr[128 + t] + c2 * asr[256 + t];
            adst[t]  = c0 * ads[t] + c1 * ads[128 + t] + c2 * ads[256 + t];
        }
        if (t < NB) bucket_pos[t] = 0;
    }
}

// ---------------------------------------------------------------------------
// pass1 body (UNCHANGED from R10)
// ---------------------------------------------------------------------------
static __device__ __forceinline__ void pass1_body(
    int blk, int* hist, int* hist2, int* gbase,
    const int* __restrict__ ei, int ne,
    int* __restrict__ bucket_pos,
    unsigned int* __restrict__ coarse)
{
    int tid = threadIdx.x;
    int b0  = blk * E_B;

    for (int i = tid; i < NB; i += 256) { hist[i] = 0; hist2[i] = 0; }

    int rows[EPTH], cols[EPTH];
    #pragma unroll
    for (int i = 0; i < EPTH; ++i) {
        int e = b0 + i * 256 + tid;            // coalesced
        cols[i] = (e < ne) ? ei[ne + e] : -1;
    }
    #pragma unroll
    for (int i = 0; i < EPTH; ++i) {
        int e = b0 + i * 256 + tid;
        rows[i] = (e < ne) ? ei[e] : 0;
    }
    __syncthreads();                           // hist zeros visible

    #pragma unroll
    for (int i = 0; i < EPTH; ++i)
        if (cols[i] >= 0) atomicAdd(&hist[cols[i] >> 8], 1);
    __syncthreads();

    for (int i = tid; i < NB; i += 256)
        gbase[i] = hist[i] ? atomicAdd(&bucket_pos[i], hist[i]) : 0;
    __syncthreads();

    #pragma unroll
    for (int i = 0; i < EPTH; ++i) {
        if (cols[i] >= 0) {
            int bk  = cols[i] >> 8;
            int pos = gbase[bk] + atomicAdd(&hist2[bk], 1);
            if (pos < CAP)
                coarse[bk * CAP + pos] =
                    ((unsigned int)cols[i] << 16) | (unsigned int)rows[i];
        }
    }
}

// ---------------------------------------------------------------------------
// gemm body (UNCHANGED from R10: wfrag staged to LDS, x loads overlap)
// ---------------------------------------------------------------------------
static __device__ __forceinline__ void gemm_body(
    int bu, float* C,
    const float* __restrict__ x,
    const unsigned int* __restrict__ wfrag,
    const float* __restrict__ biasc,
    const float* __restrict__ asrc,
    const float* __restrict__ adst,
    unsigned int* __restrict__ xtb,
    float* __restrict__ alpha_src,
    float* __restrict__ alpha_dst,
    int n)
{
    int tid  = threadIdx.x;
    int lane = tid & 63;
    int wave = tid >> 6;
    int quad = lane >> 4;
    int lm   = lane & 15;
    int m0   = bu * 64 + wave * 16;

    // stage wfrag -> LDS (2048 uint4 = 32 KB, coalesced, 8 per thread)
    uint4* wl = (uint4*)C;
    const uint4* wf = (const uint4*)wfrag;
    #pragma unroll
    for (int i = 0; i < 8; ++i)
        wl[tid + i * 256] = wf[tid + i * 256];

    // issue all 8 x-row float4 loads (overlap the staging + barrier)
    int arow = m0 + lm; if (arow >= n) arow = n - 1;   // clamp (stores masked)
    const float4* xr = (const float4*)(x + (size_t)arow * 128 + quad * 8);
    float4 a[8];
    #pragma unroll
    for (int ks = 0; ks < 4; ++ks) {
        a[2 * ks]     = xr[ks * 8 + 0];    // k = ks*32 + quad*8 + 0..3
        a[2 * ks + 1] = xr[ks * 8 + 1];    // k = ks*32 + quad*8 + 4..7
    }

    f32x4 acc[8];
    #pragma unroll
    for (int t = 0; t < 8; ++t) acc[t] = (f32x4){0.f, 0.f, 0.f, 0.f};

    __syncthreads();                       // wfrag staged

    #pragma unroll
    for (int ks = 0; ks < 4; ++ks) {
        U4 af;
        af.u.x = pack_bf16(a[2*ks].x, a[2*ks].y);
        af.u.y = pack_bf16(a[2*ks].z, a[2*ks].w);
        af.u.z = pack_bf16(a[2*ks+1].x, a[2*ks+1].y);
        af.u.w = pack_bf16(a[2*ks+1].z, a[2*ks+1].w);
        #pragma unroll
        for (int nt = 0; nt < 8; ++nt) {
            U4 bf; bf.u = wl[(nt * 4 + ks) * 64 + lane];   // LDS, bcast-free
            acc[nt] = __builtin_amdgcn_mfma_f32_16x16x32_bf16(
                af.v, bf.v, acc[nt], 0, 0, 0);
        }
    }
    __syncthreads();                       // all B-frag reads done

    // stage accumulators to LDS: C/D layout col = lane&15, row = quad*4+reg
    #pragma unroll
    for (int nt = 0; nt < 8; ++nt) {
        int col = nt * 16 + lm;
        #pragma unroll
        for (int r = 0; r < 4; ++r) {
            int rowl = wave * 16 + quad * 4 + r;
            C[rowl * 132 + col] = acc[nt][r];
        }
    }
    __syncthreads();

    // epilogue: 4 lanes per row; lane's segment = head (seg = lane&3)
    int rowl = wave * 16 + (lane >> 2);
    int seg  = lane & 3;
    int mrow = bu * 64 + rowl;
    if (mrow < n) {
        const float4* cb = (const float4*)(C + rowl * 132 + seg * 32);
        const float4* bb = (const float4*)(biasc + seg * 32);
        const float4* sb = (const float4*)(asrc + seg * 32);
        const float4* db = (const float4*)(adst + seg * 32);
        float s = 0.f, d = 0.f;
        unsigned int ow[16];
        #pragma unroll
        for (int q = 0; q < 8; ++q) {
            float4 v = cb[q];
            float4 b = bb[q];
            v.x += b.x; v.y += b.y; v.z += b.z; v.w += b.w;
            float4 as = sb[q], ad = db[q];
            s += v.x * as.x + v.y * as.y + v.z * as.z + v.w * as.w;
            d += v.x * ad.x + v.y * ad.y + v.z * ad.z + v.w * ad.w;
            ow[q * 2 + 0] = pack_bf16(v.x, v.y);
            ow[q * 2 + 1] = pack_bf16(v.z, v.w);
        }
        alpha_src[mrow * 4 + seg] = s;
        alpha_dst[mrow * 4 + seg] = d;
        uint4* xo = (uint4*)(xtb + (size_t)mrow * 64 + seg * 16);
        #pragma unroll
        for (int q4 = 0; q4 < 4; ++q4)
            xo[q4] = make_uint4(ow[q4 * 4], ow[q4 * 4 + 1],
                                ow[q4 * 4 + 2], ow[q4 * 4 + 3]);
    }
}

// ---------------------------------------------------------------------------
// Kernel 2 (fused): blocks 0..P1B-1 run pass1, the rest run gemm.
// reps>1 only for the appended DIAGNOSTIC duplicate (runs LAST: pass1 reps
// corrupt bucket_pos/coarse, which nothing reads afterward; gemm reps
// rewrite xtb/alpha identically). Barrier at rep end isolates LDS reuse.
// ---------------------------------------------------------------------------
__global__ __launch_bounds__(256) void fused_p1_gemm_kernel(
    const int* __restrict__ ei, int ne,
    int* __restrict__ bucket_pos,
    unsigned int* __restrict__ coarse,
    const float* __restrict__ x,
    const unsigned int* __restrict__ wfrag,
    const float* __restrict__ biasc,
    const float* __restrict__ asrc,
    const float* __restrict__ adst,
    unsigned int* __restrict__ xtb,
    float* __restrict__ alpha_src,
    float* __restrict__ alpha_dst,
    int n, int p1b, int reps)
{
    __shared__ __align__(16) unsigned char smem[64 * 132 * 4];   // 33 KB
    int b = blockIdx.x;
    for (int rp = 0; rp < reps; ++rp) {
        asm volatile("" ::: "memory");     // defeat cross-rep load hoisting
        if (b < p1b) {
            int* hist  = (int*)smem;
            int* hist2 = hist + NB;
            int* gbase = hist2 + NB;
            pass1_body(b, hist, hist2, gbase, ei, ne, bucket_pos, coarse);
        } else {
            gemm_body(b - p1b, (float*)smem, x, wfrag, biasc, asrc, adst,
                      xtb, alpha_src, alpha_dst, n);
        }
        __syncthreads();                   // cross-rep LDS reuse
    }
}

// ---------------------------------------------------------------------------
// window16 (UNCHANGED from R10)
// ---------------------------------------------------------------------------
static __device__ __forceinline__ void window16(
    uint4 qa, uint4 qb, int rem,
    unsigned int h, unsigned int sl, float ad,
    const unsigned int* __restrict__ xtb,
    const float* __restrict__ alpha_src,
    float& den, float4& acc)
{
    unsigned int w[8] = {qa.x, qa.y, qa.z, qa.w, qb.x, qb.y, qb.z, qb.w};
    int r[16];
    #pragma unroll
    for (int t = 0; t < 16; ++t) {
        unsigned int rr = (t & 1) ? (w[t >> 1] >> 16) : (w[t >> 1] & 0xFFFFu);
        // clamp invalid (>= rem) slots to row 0 BEFORE any address use
        r[t] = (t < rem) ? (int)rr : 0;
    }

    float as[16];
    #pragma unroll
    for (int t = 0; t < 16; ++t)
        as[t] = alpha_src[(((unsigned)r[t]) << 2) | h];
    uint2 u[16];
    #pragma unroll
    for (int t = 0; t < 16; ++t)
        u[t] = *(const uint2*)(xtb + ((((unsigned)r[t]) << 6) + (sl << 1)));

    float e[16];
    #pragma unroll
    for (int t = 0; t < 16; ++t) {
        float a = as[t] + ad;
        a = fmaxf(a, NEG_SLOPE * a);          // leaky-relu, branchless
        float ex = __expf(a);
        e[t] = (t < rem) ? ex : 0.f;          // mask padded slots
    }
    float s01 = e[0]+e[1],   s23 = e[2]+e[3],   s45 = e[4]+e[5],   s67 = e[6]+e[7];
    float s89 = e[8]+e[9],   sab = e[10]+e[11], scd = e[12]+e[13], sef = e[14]+e[15];
    den += ((s01+s23) + (s45+s67)) + ((s89+sab) + (scd+sef));

    #pragma unroll
    for (int t = 0; t < 16; ++t) {
        acc.x = fmaf(e[t], __uint_as_float(u[t].x << 16),          acc.x);
        acc.y = fmaf(e[t], __uint_as_float(u[t].x & 0xFFFF0000u),  acc.y);
        acc.z = fmaf(e[t], __uint_as_float(u[t].y << 16),          acc.z);
        acc.w = fmaf(e[t], __uint_as_float(u[t].y & 0xFFFF0000u),  acc.w);
    }
}

// ---------------------------------------------------------------------------
// Kernel 3 (pass2+agg fused, R10 structure). reps>1 only for the appended
// DIAGNOSTIC duplicate — fully idempotent (reads bucket_pos/coarse/xtb/
// alpha, rewrites identical out).
// ---------------------------------------------------------------------------
__global__ __launch_bounds__(512) void pass2agg_kernel(
    const int* __restrict__ bucket_pos,
    const unsigned int* __restrict__ coarse,
    const unsigned int* __restrict__ xtb,   // [N,64] uints (bf16 pairs)
    const float* __restrict__ alpha_src,
    const float* __restrict__ alpha_dst,
    float* __restrict__ out,          // [N,128]
    int n, int reps)
{
    __shared__ __align__(16) unsigned short st[64 * BUCKET];  // 6 KB
    __shared__ int lcnt[64];
    int b = blockIdx.x;
    int bucket = b >> 2, sub = b & 3;
    int tid = threadIdx.x;

    for (int rp = 0; rp < reps; ++rp) {
        asm volatile("" ::: "memory");     // defeat cross-rep load hoisting
        if (tid < 64) lcnt[tid] = 0;
        __syncthreads();

        // phase 1: filter this sub-range's edges out of the coarse bucket
        int cb = bucket_pos[bucket]; if (cb > CAP) cb = CAP;
        const unsigned int* cp = coarse + (size_t)bucket * CAP;
        for (int i = tid; i < cb; i += 512) {
            unsigned int v = cp[i];
            int c = (int)(v >> 16);                // global col (< 65536)
            if (((c >> 6) & 3) == sub) {
                int lc = c & 63;
                int pos = atomicAdd(&lcnt[lc], 1);
                if (pos < BUCKET)
                    st[lc * BUCKET + pos] = (unsigned short)(v & 0xFFFFu);
            }
        }
        __syncthreads();

        // phase 2: aggregation, 8 waves x 2 nodes x 4 passes = 64 nodes
        int wave = tid >> 6;
        unsigned int lane = tid & 63;
        unsigned int subn = lane >> 5;
        unsigned int sl  = lane & 31;          // channel group 4*sl .. 4*sl+3
        unsigned int h   = sl >> 3;            // 8 lanes per head
        int nbase = bucket * 256 + sub * 64;

        #pragma unroll
        for (int pass = 0; pass < 4; ++pass) {
            int ln = pass * 16 + wave * 2 + (int)subn;     // 0..63
            int node = nbase + ln;
            bool active = node < n;
            int nodec = active ? node : 0;
            int m = lcnt[ln]; if (!active) m = 0; if (m > BUCKET) m = BUCKET;
            float ad = alpha_dst[((unsigned)nodec << 2) | h];
            const uint4* sq = (const uint4*)(st + ln * BUCKET);
            uint4 qa = sq[0];
            uint4 qb = sq[1];

            float4 acc = make_float4(0.f, 0.f, 0.f, 0.f);
            float den = 0.f;
            window16(qa, qb, m, h, sl, ad, xtb, alpha_src, den, acc);
            for (int j = 16; j < m; j += 16) {         // rare: P(deg>16)~0.10
                int q = j >> 3;
                window16(sq[q], sq[q + 1], m - j, h, sl, ad, xtb, alpha_src,
                         den, acc);
            }
            if (active) {
                float inv = 1.0f / (den + 1e-16f);
                ((float4*)out)[((unsigned)node << 5) | sl] =
                    make_float4(acc.x * inv, acc.y * inv, acc.z * inv,
                                acc.w * inv);
            }
        }
        __syncthreads();                   // st/lcnt reuse by next rep
    }
}

// ---------------------------------------------------------------------------
extern "C" void kernel_launch(void* const* d_in, const int* in_sizes, int n_in,
                              void* d_out, int out_size, void* d_ws, size_t ws_size,
                              hipStream_t stream)
{
    const float* x      = (const float*)d_in[0];
    const int*   ei     = (const int*)  d_in[1];
    const float* coeffs = (const float*)d_in[2];
    const float* lw     = (const float*)d_in[3];
    const float* lb     = (const float*)d_in[4];
    const float* asr    = (const float*)d_in[5];
    const float* ads    = (const float*)d_in[6];
    float* out = (float*)d_out;

    int n  = in_sizes[0] / GAT_IN;     // 50000
    int ne = in_sizes[1] / 2;          // 600000

    // workspace layout (16B-aligned segments)
    float* ws        = (float*)d_ws;
    unsigned int* wfrag = (unsigned int*)ws;      // 8192 uints (32 KB)
    float* biasc     = ws + 16384;                // 128
    float* asrc      = ws + 16512;                // 128
    float* adst      = ws + 16640;                // 128
    unsigned int* xtb = (unsigned int*)(ws + 16768);      // n*64 uints
    float* alpha_src = (float*)(xtb + (size_t)n * 64);    // n*4
    float* alpha_dst = alpha_src + (size_t)n * 4;         // n*4
    int*   bucket_pos = (int*)(alpha_dst + (size_t)n * 4);// NB ints (pad 256)
    unsigned int* coarse = (unsigned int*)(bucket_pos + 256); // NB*CAP u32 (3.2MB)

    int p1b = (ne + E_B - 1) / E_B;    // 293 pass1 blocks
    int gu  = (n + 63) / 64;           // 782 gemm blocks

    // ======== real pipeline (identical to the 143.0 us round-10 run) ========
    interp_kernel<<<32, 256, 0, stream>>>(
        coeffs, lw, lb, asr, ads, wfrag, biasc, asrc, adst, bucket_pos);
    fused_p1_gemm_kernel<<<p1b + gu, 256, 0, stream>>>(
        ei, ne, bucket_pos, coarse,
        x, wfrag, biasc, asrc, adst, xtb, alpha_src, alpha_dst, n, p1b, 1);
    pass2agg_kernel<<<NB * 4, 512, 0, stream>>>(
        bucket_pos, coarse, xtb, alpha_src, alpha_dst, out, n, 1);

    // ======== DIAGNOSTIC duplicates (R4 playbook; removed next round).
    // Order matters: dup-pass2agg FIRST (reads still-intact bucket_pos/
    // coarse, rewrites identical out), dup-fused LAST (its pass1 reps
    // corrupt bucket_pos/coarse — nothing reads them afterward; next
    // iteration's interp re-zeros bucket_pos). Each rep > fill dur (~45us)
    // so both surface in rocprof top-5 with their true counters. ========
    pass2agg_kernel<<<NB * 4, 512, 0, stream>>>(
        bucket_pos, coarse, xtb, alpha_src, alpha_dst, out, n, 3);
    fused_p1_gemm_kernel<<<p1b + gu, 256, 0, stream>>>(
        ei, ne, bucket_pos, coarse,
        x, wfrag, biasc, asrc, adst, xtb, alpha_src, alpha_dst, n, p1b, 3);
}

// Round 13
// 142.337 us; speedup vs baseline: 2.2585x; 2.2585x over previous
//
#include <hip/hip_runtime.h>
#include <hip/hip_bf16.h>

// Problem constants
#define GAT_IN   128
#define GAT_OUT  128   // H*C
#define GAT_H    4
#define GAT_C    32
#define NEG_SLOPE 0.2f
#define BUCKET   48    // per-node edge slot capacity; P(Poisson(12) >= 48) ~ 3e-15
#define NBF      784   // fine buckets = ceil(50000/64), bucket = col>>6
#define CAPF     1024  // entries per fine bucket (mean 765, sigma 28 -> +9.3 sigma)
#define E_B      2048  // edges per pass1 block (293 blocks)
#define EPTH     8     // E_B / 256

typedef __attribute__((ext_vector_type(8))) short bf16x8;
typedef __attribute__((ext_vector_type(4))) float f32x4;
union U4 { uint4 u; bf16x8 v; };

static __device__ __forceinline__ unsigned int pack_bf16(float lo, float hi) {
    __hip_bfloat16 a = __float2bfloat16(lo);   // RTN
    __hip_bfloat16 b = __float2bfloat16(hi);
    unsigned short ua = *reinterpret_cast<unsigned short*>(&a);
    unsigned short ub = *reinterpret_cast<unsigned short*>(&b);
    return (unsigned int)ua | ((unsigned int)ub << 16);
}

// ---------------------------------------------------------------------------
// Kernel 1: Bezier param interp (32 blocks) + zero the NBF fine-bucket
// claim counters (block 0, strided).
//   wfrag uint index = ((nt*4 + ks)*64 + lane)*4 + jw
//   holds W[o = nt*16 + (lane&15)][k = ks*32 + (lane>>4)*8 + jw*2 .. +1]
// ---------------------------------------------------------------------------
__global__ __launch_bounds__(256) void interp_kernel(
    const float* __restrict__ coeffs,
    const float* __restrict__ lw,   // [3,128,128]
    const float* __restrict__ lb,   // [3,128]
    const float* __restrict__ asr,  // [3,1,4,32]
    const float* __restrict__ ads,  // [3,1,4,32]
    unsigned int* __restrict__ wfrag,  // 8192 uints (32 KB)
    float* __restrict__ biasc,
    float* __restrict__ asrc, float* __restrict__ adst,
    int* __restrict__ bucket_pos)      // [NBF] claim counters -> zero
{
    int b = blockIdx.x, t = threadIdx.x;
    int i = b * 256 + t;                    // 0..8191
    float c0 = coeffs[0], c1 = coeffs[1], c2 = coeffs[2];
    int lane = (i >> 2) & 63;
    int nk   = i >> 8;           // nt*4 + ks
    int jw   = i & 3;
    int nt = nk >> 2, ks = nk & 3;
    int o = nt * 16 + (lane & 15);
    int k = ks * 32 + (lane >> 4) * 8 + jw * 2;
    int idx = o * 128 + k;
    float w0 = c0 * lw[idx]     + c1 * lw[16384 + idx]     + c2 * lw[32768 + idx];
    float w1 = c0 * lw[idx + 1] + c1 * lw[16384 + idx + 1] + c2 * lw[32768 + idx + 1];
    wfrag[i] = pack_bf16(w0, w1);
    if (b == 0) {
        if (t < 128) {
            biasc[t] = c0 * lb[t]  + c1 * lb[128 + t]  + c2 * lb[256 + t];
            asrc[t]  = c0 * asr[t] + c1 * asr[128 + t] + c2 * asr[256 + t];
            adst[t]  = c0 * ads[t] + c1 * ads[128 + t] + c2 * ads[256 + t];
        }
        for (int j = t; j < NBF; j += 256) bucket_pos[j] = 0;
    }
}

// ---------------------------------------------------------------------------
// pass1 body: bin edges into NBF FINE buckets (bucket = col>>6) — the
// granularity agg consumes, so pass2agg reads its bucket exactly once
// (R12 measured the old 4x sub-filter redundancy inside the 35us p2agg).
// Per-block LDS histogram (3 x 784 ints = 9.2 KB), one global claim atomic
// per (block,bucket) (~215k total), packed (col<<16|row) stores into
// claimed contiguous runs.
// ---------------------------------------------------------------------------
static __device__ __forceinline__ void pass1_body(
    int blk, int* hist, int* hist2, int* gbase,
    const int* __restrict__ ei, int ne,
    int* __restrict__ bucket_pos,
    unsigned int* __restrict__ coarse)
{
    int tid = threadIdx.x;
    int b0  = blk * E_B;

    for (int i = tid; i < NBF; i += 256) { hist[i] = 0; hist2[i] = 0; }

    int rows[EPTH], cols[EPTH];
    #pragma unroll
    for (int i = 0; i < EPTH; ++i) {
        int e = b0 + i * 256 + tid;            // coalesced
        cols[i] = (e < ne) ? ei[ne + e] : -1;
    }
    #pragma unroll
    for (int i = 0; i < EPTH; ++i) {
        int e = b0 + i * 256 + tid;
        rows[i] = (e < ne) ? ei[e] : 0;
    }
    __syncthreads();                           // hist zeros visible

    #pragma unroll
    for (int i = 0; i < EPTH; ++i)
        if (cols[i] >= 0) atomicAdd(&hist[cols[i] >> 6], 1);
    __syncthreads();

    for (int i = tid; i < NBF; i += 256)
        gbase[i] = hist[i] ? atomicAdd(&bucket_pos[i], hist[i]) : 0;
    __syncthreads();

    #pragma unroll
    for (int i = 0; i < EPTH; ++i) {
        if (cols[i] >= 0) {
            int bk  = cols[i] >> 6;
            int pos = gbase[bk] + atomicAdd(&hist2[bk], 1);
            if (pos < CAPF)
                coarse[bk * CAPF + pos] =
                    ((unsigned int)cols[i] << 16) | (unsigned int)rows[i];
        }
    }
}

// ---------------------------------------------------------------------------
// gemm body (UNCHANGED from R10: wfrag staged to LDS, x loads overlap)
// ---------------------------------------------------------------------------
static __device__ __forceinline__ void gemm_body(
    int bu, float* C,
    const float* __restrict__ x,
    const unsigned int* __restrict__ wfrag,
    const float* __restrict__ biasc,
    const float* __restrict__ asrc,
    const float* __restrict__ adst,
    unsigned int* __restrict__ xtb,
    float* __restrict__ alpha_src,
    float* __restrict__ alpha_dst,
    int n)
{
    int tid  = threadIdx.x;
    int lane = tid & 63;
    int wave = tid >> 6;
    int quad = lane >> 4;
    int lm   = lane & 15;
    int m0   = bu * 64 + wave * 16;

    // stage wfrag -> LDS (2048 uint4 = 32 KB, coalesced, 8 per thread)
    uint4* wl = (uint4*)C;
    const uint4* wf = (const uint4*)wfrag;
    #pragma unroll
    for (int i = 0; i < 8; ++i)
        wl[tid + i * 256] = wf[tid + i * 256];

    // issue all 8 x-row float4 loads (overlap the staging + barrier)
    int arow = m0 + lm; if (arow >= n) arow = n - 1;   // clamp (stores masked)
    const float4* xr = (const float4*)(x + (size_t)arow * 128 + quad * 8);
    float4 a[8];
    #pragma unroll
    for (int ks = 0; ks < 4; ++ks) {
        a[2 * ks]     = xr[ks * 8 + 0];    // k = ks*32 + quad*8 + 0..3
        a[2 * ks + 1] = xr[ks * 8 + 1];    // k = ks*32 + quad*8 + 4..7
    }

    f32x4 acc[8];
    #pragma unroll
    for (int t = 0; t < 8; ++t) acc[t] = (f32x4){0.f, 0.f, 0.f, 0.f};

    __syncthreads();                       // wfrag staged

    #pragma unroll
    for (int ks = 0; ks < 4; ++ks) {
        U4 af;
        af.u.x = pack_bf16(a[2*ks].x, a[2*ks].y);
        af.u.y = pack_bf16(a[2*ks].z, a[2*ks].w);
        af.u.z = pack_bf16(a[2*ks+1].x, a[2*ks+1].y);
        af.u.w = pack_bf16(a[2*ks+1].z, a[2*ks+1].w);
        #pragma unroll
        for (int nt = 0; nt < 8; ++nt) {
            U4 bf; bf.u = wl[(nt * 4 + ks) * 64 + lane];   // LDS, bcast-free
            acc[nt] = __builtin_amdgcn_mfma_f32_16x16x32_bf16(
                af.v, bf.v, acc[nt], 0, 0, 0);
        }
    }
    __syncthreads();                       // all B-frag reads done

    // stage accumulators to LDS: C/D layout col = lane&15, row = quad*4+reg
    #pragma unroll
    for (int nt = 0; nt < 8; ++nt) {
        int col = nt * 16 + lm;
        #pragma unroll
        for (int r = 0; r < 4; ++r) {
            int rowl = wave * 16 + quad * 4 + r;
            C[rowl * 132 + col] = acc[nt][r];
        }
    }
    __syncthreads();

    // epilogue: 4 lanes per row; lane's segment = head (seg = lane&3)
    int rowl = wave * 16 + (lane >> 2);
    int seg  = lane & 3;
    int mrow = bu * 64 + rowl;
    if (mrow < n) {
        const float4* cb = (const float4*)(C + rowl * 132 + seg * 32);
        const float4* bb = (const float4*)(biasc + seg * 32);
        const float4* sb = (const float4*)(asrc + seg * 32);
        const float4* db = (const float4*)(adst + seg * 32);
        float s = 0.f, d = 0.f;
        unsigned int ow[16];
        #pragma unroll
        for (int q = 0; q < 8; ++q) {
            float4 v = cb[q];
            float4 b = bb[q];
            v.x += b.x; v.y += b.y; v.z += b.z; v.w += b.w;
            float4 as = sb[q], ad = db[q];
            s += v.x * as.x + v.y * as.y + v.z * as.z + v.w * as.w;
            d += v.x * ad.x + v.y * ad.y + v.z * ad.z + v.w * ad.w;
            ow[q * 2 + 0] = pack_bf16(v.x, v.y);
            ow[q * 2 + 1] = pack_bf16(v.z, v.w);
        }
        alpha_src[mrow * 4 + seg] = s;
        alpha_dst[mrow * 4 + seg] = d;
        uint4* xo = (uint4*)(xtb + (size_t)mrow * 64 + seg * 16);
        #pragma unroll
        for (int q4 = 0; q4 < 4; ++q4)
            xo[q4] = make_uint4(ow[q4 * 4], ow[q4 * 4 + 1],
                                ow[q4 * 4 + 2], ow[q4 * 4 + 3]);
    }
}

// ---------------------------------------------------------------------------
// Kernel 2 (fused): blocks 0..P1B-1 run pass1, the rest run gemm.
// LDS = 33KB union (gemm C tile / pass1 3x784-int histograms = 9.2 KB).
// ---------------------------------------------------------------------------
__global__ __launch_bounds__(256) void fused_p1_gemm_kernel(
    const int* __restrict__ ei, int ne,
    int* __restrict__ bucket_pos,
    unsigned int* __restrict__ coarse,
    const float* __restrict__ x,
    const unsigned int* __restrict__ wfrag,
    const float* __restrict__ biasc,
    const float* __restrict__ asrc,
    const float* __restrict__ adst,
    unsigned int* __restrict__ xtb,
    float* __restrict__ alpha_src,
    float* __restrict__ alpha_dst,
    int n, int p1b)
{
    __shared__ __align__(16) unsigned char smem[64 * 132 * 4];   // 33 KB
    int b = blockIdx.x;
    if (b < p1b) {
        int* hist  = (int*)smem;
        int* hist2 = hist + NBF;
        int* gbase = hist2 + NBF;
        pass1_body(b, hist, hist2, gbase, ei, ne, bucket_pos, coarse);
    } else {
        gemm_body(b - p1b, (float*)smem, x, wfrag, biasc, asrc, adst,
                  xtb, alpha_src, alpha_dst, n);
    }
}

// ---------------------------------------------------------------------------
// window16 (UNCHANGED gather core)
// ---------------------------------------------------------------------------
static __device__ __forceinline__ void window16(
    uint4 qa, uint4 qb, int rem,
    unsigned int h, unsigned int sl, float ad,
    const unsigned int* __restrict__ xtb,
    const float* __restrict__ alpha_src,
    float& den, float4& acc)
{
    unsigned int w[8] = {qa.x, qa.y, qa.z, qa.w, qb.x, qb.y, qb.z, qb.w};
    int r[16];
    #pragma unroll
    for (int t = 0; t < 16; ++t) {
        unsigned int rr = (t & 1) ? (w[t >> 1] >> 16) : (w[t >> 1] & 0xFFFFu);
        // clamp invalid (>= rem) slots to row 0 BEFORE any address use
        r[t] = (t < rem) ? (int)rr : 0;
    }

    float as[16];
    #pragma unroll
    for (int t = 0; t < 16; ++t)
        as[t] = alpha_src[(((unsigned)r[t]) << 2) | h];
    uint2 u[16];
    #pragma unroll
    for (int t = 0; t < 16; ++t)
        u[t] = *(const uint2*)(xtb + ((((unsigned)r[t]) << 6) + (sl << 1)));

    float e[16];
    #pragma unroll
    for (int t = 0; t < 16; ++t) {
        float a = as[t] + ad;
        a = fmaxf(a, NEG_SLOPE * a);          // leaky-relu, branchless
        float ex = __expf(a);
        e[t] = (t < rem) ? ex : 0.f;          // mask padded slots
    }
    float s01 = e[0]+e[1],   s23 = e[2]+e[3],   s45 = e[4]+e[5],   s67 = e[6]+e[7];
    float s89 = e[8]+e[9],   sab = e[10]+e[11], scd = e[12]+e[13], sef = e[14]+e[15];
    den += ((s01+s23) + (s45+s67)) + ((s89+sab) + (scd+sef));

    #pragma unroll
    for (int t = 0; t < 16; ++t) {
        acc.x = fmaf(e[t], __uint_as_float(u[t].x << 16),          acc.x);
        acc.y = fmaf(e[t], __uint_as_float(u[t].x & 0xFFFF0000u),  acc.y);
        acc.z = fmaf(e[t], __uint_as_float(u[t].y << 16),          acc.z);
        acc.w = fmaf(e[t], __uint_as_float(u[t].y & 0xFFFF0000u),  acc.w);
    }
}

// ---------------------------------------------------------------------------
// Kernel 3 (pass2+agg): one block per FINE bucket (64 nodes, 512 threads,
// 784 blocks). Phase 1: read this bucket's entries exactly ONCE (~765
// entries, 2/thread — no 4x sub-filter redundancy, R12's measured waste),
// LDS-atomic them into st[64][48] + lcnt. Phase 2: window16 aggregation,
// 8 waves x 2 nodes x 4 passes = 64 nodes (unchanged gather core).
// ---------------------------------------------------------------------------
__global__ __launch_bounds__(512) void pass2agg_kernel(
    const int* __restrict__ bucket_pos,
    const unsigned int* __restrict__ coarse,
    const unsigned int* __restrict__ xtb,   // [N,64] uints (bf16 pairs)
    const float* __restrict__ alpha_src,
    const float* __restrict__ alpha_dst,
    float* __restrict__ out,          // [N,128]
    int n)
{
    __shared__ __align__(16) unsigned short st[64 * BUCKET];  // 6 KB
    __shared__ int lcnt[64];
    int b = blockIdx.x;                    // fine bucket = 64 nodes
    int tid = threadIdx.x;
    if (tid < 64) lcnt[tid] = 0;
    __syncthreads();

    // phase 1: single scan of this bucket's entries
    int cb = bucket_pos[b]; if (cb > CAPF) cb = CAPF;
    const unsigned int* cp = coarse + (size_t)b * CAPF;
    for (int i = tid; i < cb; i += 512) {
        unsigned int v = cp[i];
        int lc = (int)(v >> 16) & 63;          // col % 64 (bucket = col>>6)
        int pos = atomicAdd(&lcnt[lc], 1);
        if (pos < BUCKET)
            st[lc * BUCKET + pos] = (unsigned short)(v & 0xFFFFu);
    }
    __syncthreads();

    // phase 2: aggregation, 8 waves x 2 nodes x 4 passes = 64 nodes
    int wave = tid >> 6;
    unsigned int lane = tid & 63;
    unsigned int subn = lane >> 5;
    unsigned int sl  = lane & 31;          // channel group 4*sl .. 4*sl+3
    unsigned int h   = sl >> 3;            // 8 lanes per head
    int nbase = b * 64;

    #pragma unroll
    for (int pass = 0; pass < 4; ++pass) {
        int ln = pass * 16 + wave * 2 + (int)subn;     // 0..63
        int node = nbase + ln;
        bool active = node < n;
        int nodec = active ? node : 0;
        int m = lcnt[ln]; if (!active) m = 0; if (m > BUCKET) m = BUCKET;
        float ad = alpha_dst[((unsigned)nodec << 2) | h];
        const uint4* sq = (const uint4*)(st + ln * BUCKET);
        uint4 qa = sq[0];
        uint4 qb = sq[1];

        float4 acc = make_float4(0.f, 0.f, 0.f, 0.f);
        float den = 0.f;
        window16(qa, qb, m, h, sl, ad, xtb, alpha_src, den, acc);
        for (int j = 16; j < m; j += 16) {             // rare: P(deg>16)~0.10
            int q = j >> 3;
            window16(sq[q], sq[q + 1], m - j, h, sl, ad, xtb, alpha_src,
                     den, acc);
        }
        if (active) {
            float inv = 1.0f / (den + 1e-16f);
            ((float4*)out)[((unsigned)node << 5) | sl] =
                make_float4(acc.x * inv, acc.y * inv, acc.z * inv,
                            acc.w * inv);
        }
    }
}

// ---------------------------------------------------------------------------
extern "C" void kernel_launch(void* const* d_in, const int* in_sizes, int n_in,
                              void* d_out, int out_size, void* d_ws, size_t ws_size,
                              hipStream_t stream)
{
    const float* x      = (const float*)d_in[0];
    const int*   ei     = (const int*)  d_in[1];
    const float* coeffs = (const float*)d_in[2];
    const float* lw     = (const float*)d_in[3];
    const float* lb     = (const float*)d_in[4];
    const float* asr    = (const float*)d_in[5];
    const float* ads    = (const float*)d_in[6];
    float* out = (float*)d_out;

    int n  = in_sizes[0] / GAT_IN;     // 50000
    int ne = in_sizes[1] / 2;          // 600000

    // workspace layout (16B-aligned segments)
    float* ws        = (float*)d_ws;
    unsigned int* wfrag = (unsigned int*)ws;      // 8192 uints (32 KB)
    float* biasc     = ws + 16384;                // 128
    float* asrc      = ws + 16512;                // 128
    float* adst      = ws + 16640;                // 128
    unsigned int* xtb = (unsigned int*)(ws + 16768);      // n*64 uints
    float* alpha_src = (float*)(xtb + (size_t)n * 64);    // n*4
    float* alpha_dst = alpha_src + (size_t)n * 4;         // n*4
    int*   bucket_pos = (int*)(alpha_dst + (size_t)n * 4);// NBF ints (pad 1024)
    unsigned int* coarse = (unsigned int*)(bucket_pos + 1024); // NBF*CAPF u32 (3.2MB)

    int p1b = (ne + E_B - 1) / E_B;    // 293 pass1 blocks
    int gu  = (n + 63) / 64;           // 782 gemm blocks

    // 1. param interp + zero claim counters
    interp_kernel<<<32, 256, 0, stream>>>(
        coeffs, lw, lb, asr, ads, wfrag, biasc, asrc, adst, bucket_pos);
    // 2. fused {pass1 fine binning || MFMA gemm (wfrag via LDS)}
    fused_p1_gemm_kernel<<<p1b + gu, 256, 0, stream>>>(
        ei, ne, bucket_pos, coarse,
        x, wfrag, biasc, asrc, adst, xtb, alpha_src, alpha_dst, n, p1b);
    // 3. pass2+agg: one block per fine bucket, single-scan staging
    pass2agg_kernel<<<NBF, 512, 0, stream>>>(
        bucket_pos, coarse, xtb, alpha_src, alpha_dst, out, n);
}

// Round 14
// 141.928 us; speedup vs baseline: 2.2650x; 1.0029x over previous
//
#include <hip/hip_runtime.h>
#include <hip/hip_bf16.h>

// Problem constants
#define GAT_IN   128
#define GAT_OUT  128   // H*C
#define GAT_H    4
#define GAT_C    32
#define NEG_SLOPE 0.2f
#define BUCKET   48    // per-node edge slot capacity; P(Poisson(12) >= 48) ~ 3e-15
#define NBF      1563  // fine buckets = ceil(50000/32), bucket = col>>5
#define NBPAD    1568  // padded hist size
#define CAPF     640   // entries per fine bucket (mean 382, sigma 19.5 -> +13 sigma)
#define E_B      2048  // edges per pass1 block (293 blocks)
#define EPTH     8     // E_B / 256

typedef __attribute__((ext_vector_type(8))) short bf16x8;
typedef __attribute__((ext_vector_type(4))) float f32x4;
union U4 { uint4 u; bf16x8 v; };

static __device__ __forceinline__ unsigned int pack_bf16(float lo, float hi) {
    __hip_bfloat16 a = __float2bfloat16(lo);   // RTN
    __hip_bfloat16 b = __float2bfloat16(hi);
    unsigned short ua = *reinterpret_cast<unsigned short*>(&a);
    unsigned short ub = *reinterpret_cast<unsigned short*>(&b);
    return (unsigned int)ua | ((unsigned int)ub << 16);
}

// ---------------------------------------------------------------------------
// Kernel 1: Bezier param interp (32 blocks) + zero the NBF fine-bucket
// claim counters (block 0, strided).
//   wfrag uint index = ((nt*4 + ks)*64 + lane)*4 + jw
//   holds W[o = nt*16 + (lane&15)][k = ks*32 + (lane>>4)*8 + jw*2 .. +1]
// ---------------------------------------------------------------------------
__global__ __launch_bounds__(256) void interp_kernel(
    const float* __restrict__ coeffs,
    const float* __restrict__ lw,   // [3,128,128]
    const float* __restrict__ lb,   // [3,128]
    const float* __restrict__ asr,  // [3,1,4,32]
    const float* __restrict__ ads,  // [3,1,4,32]
    unsigned int* __restrict__ wfrag,  // 8192 uints (32 KB)
    float* __restrict__ biasc,
    float* __restrict__ asrc, float* __restrict__ adst,
    int* __restrict__ bucket_pos)      // [NBPAD] claim counters -> zero
{
    int b = blockIdx.x, t = threadIdx.x;
    int i = b * 256 + t;                    // 0..8191
    float c0 = coeffs[0], c1 = coeffs[1], c2 = coeffs[2];
    int lane = (i >> 2) & 63;
    int nk   = i >> 8;           // nt*4 + ks
    int jw   = i & 3;
    int nt = nk >> 2, ks = nk & 3;
    int o = nt * 16 + (lane & 15);
    int k = ks * 32 + (lane >> 4) * 8 + jw * 2;
    int idx = o * 128 + k;
    float w0 = c0 * lw[idx]     + c1 * lw[16384 + idx]     + c2 * lw[32768 + idx];
    float w1 = c0 * lw[idx + 1] + c1 * lw[16384 + idx + 1] + c2 * lw[32768 + idx + 1];
    wfrag[i] = pack_bf16(w0, w1);
    if (b == 0) {
        if (t < 128) {
            biasc[t] = c0 * lb[t]  + c1 * lb[128 + t]  + c2 * lb[256 + t];
            asrc[t]  = c0 * asr[t] + c1 * asr[128 + t] + c2 * asr[256 + t];
            adst[t]  = c0 * ads[t] + c1 * ads[128 + t] + c2 * ads[256 + t];
        }
        for (int j = t; j < NBPAD; j += 256) bucket_pos[j] = 0;
    }
}

// ---------------------------------------------------------------------------
// pass1 body: bin edges into NBF FINE buckets (bucket = col>>5) — the
// granularity agg consumes. Per-block LDS histogram (3 x 1568 ints =
// 18.8 KB), one global claim atomic per (block,nonzero-bucket) (~333k),
// packed (col<<16|row) stores into claimed contiguous runs.
// ---------------------------------------------------------------------------
static __device__ __forceinline__ void pass1_body(
    int blk, int* hist, int* hist2, int* gbase,
    const int* __restrict__ ei, int ne,
    int* __restrict__ bucket_pos,
    unsigned int* __restrict__ coarse)
{
    int tid = threadIdx.x;
    int b0  = blk * E_B;

    for (int i = tid; i < NBPAD; i += 256) { hist[i] = 0; hist2[i] = 0; }

    int rows[EPTH], cols[EPTH];
    #pragma unroll
    for (int i = 0; i < EPTH; ++i) {
        int e = b0 + i * 256 + tid;            // coalesced
        cols[i] = (e < ne) ? ei[ne + e] : -1;
    }
    #pragma unroll
    for (int i = 0; i < EPTH; ++i) {
        int e = b0 + i * 256 + tid;
        rows[i] = (e < ne) ? ei[e] : 0;
    }
    __syncthreads();                           // hist zeros visible

    #pragma unroll
    for (int i = 0; i < EPTH; ++i)
        if (cols[i] >= 0) atomicAdd(&hist[cols[i] >> 5], 1);
    __syncthreads();

    for (int i = tid; i < NBPAD; i += 256)
        gbase[i] = hist[i] ? atomicAdd(&bucket_pos[i], hist[i]) : 0;
    __syncthreads();

    #pragma unroll
    for (int i = 0; i < EPTH; ++i) {
        if (cols[i] >= 0) {
            int bk  = cols[i] >> 5;
            int pos = gbase[bk] + atomicAdd(&hist2[bk], 1);
            if (pos < CAPF)
                coarse[bk * CAPF + pos] =
                    ((unsigned int)cols[i] << 16) | (unsigned int)rows[i];
        }
    }
}

// ---------------------------------------------------------------------------
// gemm body (UNCHANGED from R10: wfrag staged to LDS, x loads overlap)
// ---------------------------------------------------------------------------
static __device__ __forceinline__ void gemm_body(
    int bu, float* C,
    const float* __restrict__ x,
    const unsigned int* __restrict__ wfrag,
    const float* __restrict__ biasc,
    const float* __restrict__ asrc,
    const float* __restrict__ adst,
    unsigned int* __restrict__ xtb,
    float* __restrict__ alpha_src,
    float* __restrict__ alpha_dst,
    int n)
{
    int tid  = threadIdx.x;
    int lane = tid & 63;
    int wave = tid >> 6;
    int quad = lane >> 4;
    int lm   = lane & 15;
    int m0   = bu * 64 + wave * 16;

    // stage wfrag -> LDS (2048 uint4 = 32 KB, coalesced, 8 per thread)
    uint4* wl = (uint4*)C;
    const uint4* wf = (const uint4*)wfrag;
    #pragma unroll
    for (int i = 0; i < 8; ++i)
        wl[tid + i * 256] = wf[tid + i * 256];

    // issue all 8 x-row float4 loads (overlap the staging + barrier)
    int arow = m0 + lm; if (arow >= n) arow = n - 1;   // clamp (stores masked)
    const float4* xr = (const float4*)(x + (size_t)arow * 128 + quad * 8);
    float4 a[8];
    #pragma unroll
    for (int ks = 0; ks < 4; ++ks) {
        a[2 * ks]     = xr[ks * 8 + 0];    // k = ks*32 + quad*8 + 0..3
        a[2 * ks + 1] = xr[ks * 8 + 1];    // k = ks*32 + quad*8 + 4..7
    }

    f32x4 acc[8];
    #pragma unroll
    for (int t = 0; t < 8; ++t) acc[t] = (f32x4){0.f, 0.f, 0.f, 0.f};

    __syncthreads();                       // wfrag staged

    #pragma unroll
    for (int ks = 0; ks < 4; ++ks) {
        U4 af;
        af.u.x = pack_bf16(a[2*ks].x, a[2*ks].y);
        af.u.y = pack_bf16(a[2*ks].z, a[2*ks].w);
        af.u.z = pack_bf16(a[2*ks+1].x, a[2*ks+1].y);
        af.u.w = pack_bf16(a[2*ks+1].z, a[2*ks+1].w);
        #pragma unroll
        for (int nt = 0; nt < 8; ++nt) {
            U4 bf; bf.u = wl[(nt * 4 + ks) * 64 + lane];   // LDS, bcast-free
            acc[nt] = __builtin_amdgcn_mfma_f32_16x16x32_bf16(
                af.v, bf.v, acc[nt], 0, 0, 0);
        }
    }
    __syncthreads();                       // all B-frag reads done

    // stage accumulators to LDS: C/D layout col = lane&15, row = quad*4+reg
    #pragma unroll
    for (int nt = 0; nt < 8; ++nt) {
        int col = nt * 16 + lm;
        #pragma unroll
        for (int r = 0; r < 4; ++r) {
            int rowl = wave * 16 + quad * 4 + r;
            C[rowl * 132 + col] = acc[nt][r];
        }
    }
    __syncthreads();

    // epilogue: 4 lanes per row; lane's segment = head (seg = lane&3)
    int rowl = wave * 16 + (lane >> 2);
    int seg  = lane & 3;
    int mrow = bu * 64 + rowl;
    if (mrow < n) {
        const float4* cb = (const float4*)(C + rowl * 132 + seg * 32);
        const float4* bb = (const float4*)(biasc + seg * 32);
        const float4* sb = (const float4*)(asrc + seg * 32);
        const float4* db = (const float4*)(adst + seg * 32);
        float s = 0.f, d = 0.f;
        unsigned int ow[16];
        #pragma unroll
        for (int q = 0; q < 8; ++q) {
            float4 v = cb[q];
            float4 b = bb[q];
            v.x += b.x; v.y += b.y; v.z += b.z; v.w += b.w;
            float4 as = sb[q], ad = db[q];
            s += v.x * as.x + v.y * as.y + v.z * as.z + v.w * as.w;
            d += v.x * ad.x + v.y * ad.y + v.z * ad.z + v.w * ad.w;
            ow[q * 2 + 0] = pack_bf16(v.x, v.y);
            ow[q * 2 + 1] = pack_bf16(v.z, v.w);
        }
        alpha_src[mrow * 4 + seg] = s;
        alpha_dst[mrow * 4 + seg] = d;
        uint4* xo = (uint4*)(xtb + (size_t)mrow * 64 + seg * 16);
        #pragma unroll
        for (int q4 = 0; q4 < 4; ++q4)
            xo[q4] = make_uint4(ow[q4 * 4], ow[q4 * 4 + 1],
                                ow[q4 * 4 + 2], ow[q4 * 4 + 3]);
    }
}

// ---------------------------------------------------------------------------
// Kernel 2 (fused): blocks 0..P1B-1 run pass1, the rest run gemm.
// LDS = 33KB union (gemm C tile / pass1 3x1568-int histograms = 18.8 KB).
// ---------------------------------------------------------------------------
__global__ __launch_bounds__(256) void fused_p1_gemm_kernel(
    const int* __restrict__ ei, int ne,
    int* __restrict__ bucket_pos,
    unsigned int* __restrict__ coarse,
    const float* __restrict__ x,
    const unsigned int* __restrict__ wfrag,
    const float* __restrict__ biasc,
    const float* __restrict__ asrc,
    const float* __restrict__ adst,
    unsigned int* __restrict__ xtb,
    float* __restrict__ alpha_src,
    float* __restrict__ alpha_dst,
    int n, int p1b)
{
    __shared__ __align__(16) unsigned char smem[64 * 132 * 4];   // 33 KB
    int b = blockIdx.x;
    if (b < p1b) {
        int* hist  = (int*)smem;
        int* hist2 = hist + NBPAD;
        int* gbase = hist2 + NBPAD;
        pass1_body(b, hist, hist2, gbase, ei, ne, bucket_pos, coarse);
    } else {
        gemm_body(b - p1b, (float*)smem, x, wfrag, biasc, asrc, adst,
                  xtb, alpha_src, alpha_dst, n);
    }
}

// ---------------------------------------------------------------------------
// window16 (UNCHANGED gather core)
// ---------------------------------------------------------------------------
static __device__ __forceinline__ void window16(
    uint4 qa, uint4 qb, int rem,
    unsigned int h, unsigned int sl, float ad,
    const unsigned int* __restrict__ xtb,
    const float* __restrict__ alpha_src,
    float& den, float4& acc)
{
    unsigned int w[8] = {qa.x, qa.y, qa.z, qa.w, qb.x, qb.y, qb.z, qb.w};
    int r[16];
    #pragma unroll
    for (int t = 0; t < 16; ++t) {
        unsigned int rr = (t & 1) ? (w[t >> 1] >> 16) : (w[t >> 1] & 0xFFFFu);
        // clamp invalid (>= rem) slots to row 0 BEFORE any address use
        r[t] = (t < rem) ? (int)rr : 0;
    }

    float as[16];
    #pragma unroll
    for (int t = 0; t < 16; ++t)
        as[t] = alpha_src[(((unsigned)r[t]) << 2) | h];
    uint2 u[16];
    #pragma unroll
    for (int t = 0; t < 16; ++t)
        u[t] = *(const uint2*)(xtb + ((((unsigned)r[t]) << 6) + (sl << 1)));

    float e[16];
    #pragma unroll
    for (int t = 0; t < 16; ++t) {
        float a = as[t] + ad;
        a = fmaxf(a, NEG_SLOPE * a);          // leaky-relu, branchless
        float ex = __expf(a);
        e[t] = (t < rem) ? ex : 0.f;          // mask padded slots
    }
    float s01 = e[0]+e[1],   s23 = e[2]+e[3],   s45 = e[4]+e[5],   s67 = e[6]+e[7];
    float s89 = e[8]+e[9],   sab = e[10]+e[11], scd = e[12]+e[13], sef = e[14]+e[15];
    den += ((s01+s23) + (s45+s67)) + ((s89+sab) + (scd+sef));

    #pragma unroll
    for (int t = 0; t < 16; ++t) {
        acc.x = fmaf(e[t], __uint_as_float(u[t].x << 16),          acc.x);
        acc.y = fmaf(e[t], __uint_as_float(u[t].x & 0xFFFF0000u),  acc.y);
        acc.z = fmaf(e[t], __uint_as_float(u[t].y << 16),          acc.z);
        acc.w = fmaf(e[t], __uint_as_float(u[t].y & 0xFFFF0000u),  acc.w);
    }
}

// ---------------------------------------------------------------------------
// Kernel 3 (pass2+agg): one block per FINE bucket (32 nodes, 256 threads,
// 1563 blocks). R14: halved block size — 256-thr blocks allow 8 blocks/CU
// (R12 measured p2agg at 29% occupancy with 512-thr/784-block shape; the
// gather loop is latency-bound and under-hidden). Phase 1: single scan of
// this bucket's ~382 entries into st[32][48] + lcnt via LDS atomics.
// Phase 2: window16 aggregation, 4 waves x 2 nodes x 4 passes = 32 nodes.
// ---------------------------------------------------------------------------
__global__ __launch_bounds__(256) void pass2agg_kernel(
    const int* __restrict__ bucket_pos,
    const unsigned int* __restrict__ coarse,
    const unsigned int* __restrict__ xtb,   // [N,64] uints (bf16 pairs)
    const float* __restrict__ alpha_src,
    const float* __restrict__ alpha_dst,
    float* __restrict__ out,          // [N,128]
    int n)
{
    __shared__ __align__(16) unsigned short st[32 * BUCKET];  // 3 KB
    __shared__ int lcnt[32];
    int b = blockIdx.x;                    // fine bucket = 32 nodes
    int tid = threadIdx.x;
    if (tid < 32) lcnt[tid] = 0;
    __syncthreads();

    // phase 1: single scan of this bucket's entries (~382, 1.5/thread)
    int cb = bucket_pos[b]; if (cb > CAPF) cb = CAPF;
    const unsigned int* cp = coarse + (size_t)b * CAPF;
    for (int i = tid; i < cb; i += 256) {
        unsigned int v = cp[i];
        int lc = (int)(v >> 16) & 31;          // col % 32 (bucket = col>>5)
        int pos = atomicAdd(&lcnt[lc], 1);
        if (pos < BUCKET)
            st[lc * BUCKET + pos] = (unsigned short)(v & 0xFFFFu);
    }
    __syncthreads();

    // phase 2: aggregation, 4 waves x 2 nodes x 4 passes = 32 nodes
    int wave = tid >> 6;
    unsigned int lane = tid & 63;
    unsigned int subn = lane >> 5;
    unsigned int sl  = lane & 31;          // channel group 4*sl .. 4*sl+3
    unsigned int h   = sl >> 3;            // 8 lanes per head
    int nbase = b * 32;

    #pragma unroll
    for (int pass = 0; pass < 4; ++pass) {
        int ln = pass * 8 + wave * 2 + (int)subn;      // 0..31
        int node = nbase + ln;
        bool active = node < n;
        int nodec = active ? node : 0;
        int m = lcnt[ln]; if (!active) m = 0; if (m > BUCKET) m = BUCKET;
        float ad = alpha_dst[((unsigned)nodec << 2) | h];
        const uint4* sq = (const uint4*)(st + ln * BUCKET);
        uint4 qa = sq[0];
        uint4 qb = sq[1];

        float4 acc = make_float4(0.f, 0.f, 0.f, 0.f);
        float den = 0.f;
        window16(qa, qb, m, h, sl, ad, xtb, alpha_src, den, acc);
        for (int j = 16; j < m; j += 16) {             // rare: P(deg>16)~0.10
            int q = j >> 3;
            window16(sq[q], sq[q + 1], m - j, h, sl, ad, xtb, alpha_src,
                     den, acc);
        }
        if (active) {
            float inv = 1.0f / (den + 1e-16f);
            ((float4*)out)[((unsigned)node << 5) | sl] =
                make_float4(acc.x * inv, acc.y * inv, acc.z * inv,
                            acc.w * inv);
        }
    }
}

// ---------------------------------------------------------------------------
extern "C" void kernel_launch(void* const* d_in, const int* in_sizes, int n_in,
                              void* d_out, int out_size, void* d_ws, size_t ws_size,
                              hipStream_t stream)
{
    const float* x      = (const float*)d_in[0];
    const int*   ei     = (const int*)  d_in[1];
    const float* coeffs = (const float*)d_in[2];
    const float* lw     = (const float*)d_in[3];
    const float* lb     = (const float*)d_in[4];
    const float* asr    = (const float*)d_in[5];
    const float* ads    = (const float*)d_in[6];
    float* out = (float*)d_out;

    int n  = in_sizes[0] / GAT_IN;     // 50000
    int ne = in_sizes[1] / 2;          // 600000

    // workspace layout (16B-aligned segments)
    float* ws        = (float*)d_ws;
    unsigned int* wfrag = (unsigned int*)ws;      // 8192 uints (32 KB)
    float* biasc     = ws + 16384;                // 128
    float* asrc      = ws + 16512;                // 128
    float* adst      = ws + 16640;                // 128
    unsigned int* xtb = (unsigned int*)(ws + 16768);      // n*64 uints
    float* alpha_src = (float*)(xtb + (size_t)n * 64);    // n*4
    float* alpha_dst = alpha_src + (size_t)n * 4;         // n*4
    int*   bucket_pos = (int*)(alpha_dst + (size_t)n * 4);// NBPAD ints (pad 2048)
    unsigned int* coarse = (unsigned int*)(bucket_pos + 2048); // NBF*CAPF u32 (4MB)

    int p1b = (ne + E_B - 1) / E_B;    // 293 pass1 blocks
    int gu  = (n + 63) / 64;           // 782 gemm blocks

    // 1. param interp + zero claim counters
    interp_kernel<<<32, 256, 0, stream>>>(
        coeffs, lw, lb, asr, ads, wfrag, biasc, asrc, adst, bucket_pos);
    // 2. fused {pass1 fine binning || MFMA gemm (wfrag via LDS)}
    fused_p1_gemm_kernel<<<p1b + gu, 256, 0, stream>>>(
        ei, ne, bucket_pos, coarse,
        x, wfrag, biasc, asrc, adst, xtb, alpha_src, alpha_dst, n, p1b);
    // 3. pass2+agg: one 256-thr block per 32-node fine bucket (occupancy)
    pass2agg_kernel<<<NBF, 256, 0, stream>>>(
        bucket_pos, coarse, xtb, alpha_src, alpha_dst, out, n);
}